// Round 1
// baseline (2461.430 us; speedup 1.0000x reference)
//
#include <hip/hip_runtime.h>
#include <math.h>

#define B_    16
#define N_    577
#define C_    768
#define H_    12
#define HD_   64
#define M_    (B_ * N_)          // 9232
#define QKV_N 2304
#define NIMG  576

// ---- workspace layout (in floats) ----
#define OFF_QKV     0u                          // 9232*2304 = 21,270,528
#define OFF_ATTNOUT 21270528u                   // + 9232*768 = 7,090,176
#define OFF_XOUT    28360704u                   // + 7,090,176
#define OFF_CLS     35450880u                   // + 16*576 = 9216
#define OFF_META    35460096u                   // ints: meta[8], keep_idx[576], img_idx[9216]
// total ≈ 135.4 MiB of workspace

// ======================= SGEMM: C = A @ B^T (+bias) =======================
// A: [M,768] row-major, Bw: [Nout,768] row-major, Cout: [M,Nout]
__global__ __launch_bounds__(256) void sgemm_nt(const float* __restrict__ A,
                                                const float* __restrict__ Bw,
                                                const float* __restrict__ bias,
                                                float* __restrict__ Cout,
                                                int M, int Nout) {
    const int K = 768;
    __shared__ float As[8][128];
    __shared__ float Bs[8][128];
    int tid = threadIdx.x;
    int tx = tid & 15, ty = tid >> 4;
    int m0 = blockIdx.y * 128, n0 = blockIdx.x * 128;
    int ar = tid >> 1;
    int ac = (tid & 1) << 2;

    float c[8][8];
#pragma unroll
    for (int i = 0; i < 8; ++i)
#pragma unroll
        for (int j = 0; j < 8; ++j) c[i][j] = 0.f;

    const float* Aptr = A + (size_t)(m0 + ar) * K + ac;
    const float* Bptr = Bw + (size_t)(n0 + ar) * K + ac;
    bool aval = (m0 + ar) < M;
    bool bval = (n0 + ar) < Nout;

    for (int k0 = 0; k0 < K; k0 += 8) {
        float4 av = aval ? *(const float4*)(Aptr + k0) : float4{0.f, 0.f, 0.f, 0.f};
        float4 bv = bval ? *(const float4*)(Bptr + k0) : float4{0.f, 0.f, 0.f, 0.f};
        __syncthreads();
        As[ac + 0][ar] = av.x; As[ac + 1][ar] = av.y; As[ac + 2][ar] = av.z; As[ac + 3][ar] = av.w;
        Bs[ac + 0][ar] = bv.x; Bs[ac + 1][ar] = bv.y; Bs[ac + 2][ar] = bv.z; Bs[ac + 3][ar] = bv.w;
        __syncthreads();
#pragma unroll
        for (int kk = 0; kk < 8; ++kk) {
            float a[8], bb[8];
            *(float4*)&a[0]  = *(const float4*)&As[kk][ty * 8];
            *(float4*)&a[4]  = *(const float4*)&As[kk][ty * 8 + 4];
            *(float4*)&bb[0] = *(const float4*)&Bs[kk][tx * 8];
            *(float4*)&bb[4] = *(const float4*)&Bs[kk][tx * 8 + 4];
#pragma unroll
            for (int i = 0; i < 8; ++i)
#pragma unroll
                for (int j = 0; j < 8; ++j) c[i][j] = fmaf(a[i], bb[j], c[i][j]);
        }
    }

    int mbase = m0 + ty * 8;
    int nbase = n0 + tx * 8;
    float bvals[8];
#pragma unroll
    for (int j = 0; j < 8; ++j) bvals[j] = 0.f;
    if (bias) {
#pragma unroll
        for (int j = 0; j < 8; ++j) bvals[j] = bias[nbase + j];
    }
#pragma unroll
    for (int i = 0; i < 8; ++i) {
        int m = mbase + i;
        if (m < M) {
            float4 r0 = {c[i][0] + bvals[0], c[i][1] + bvals[1], c[i][2] + bvals[2], c[i][3] + bvals[3]};
            float4 r1 = {c[i][4] + bvals[4], c[i][5] + bvals[5], c[i][6] + bvals[6], c[i][7] + bvals[7]};
            float* dst = Cout + (size_t)m * Nout + nbase;
            *(float4*)dst = r0;
            *(float4*)(dst + 4) = r1;
        }
    }
}

// ======================= fused attention =======================
// grid: (19 row-tiles, B*H). qkv layout: [b*N + n][3*768] with q|k|v at +0|+768|+1536, col h*64+d
__global__ __launch_bounds__(256) void attn_fused(const float* __restrict__ qkv,
                                                  const float* __restrict__ bias_table,
                                                  const int* __restrict__ rel_index,
                                                  float* __restrict__ attn_out) {
    int bh = blockIdx.y;
    int b = bh / H_, h = bh % H_;
    int row0 = blockIdx.x * 32;
    __shared__ float qs[32][68];
    __shared__ float ks[64][68];
    __shared__ float vs[64][68];
    __shared__ float sc[32][68];
    int tid = threadIdx.x;
    int r  = tid >> 3;          // 0..31  (phase 2/3 row)
    int cl = tid & 7;           // 0..7
    int cs = cl << 3;           // 0..56

    { // load Q tile (scaled)
        int row = row0 + r;
        float4 v0 = {0.f, 0.f, 0.f, 0.f}, v1 = {0.f, 0.f, 0.f, 0.f};
        if (row < N_) {
            const float* src = qkv + (size_t)(b * N_ + row) * QKV_N + h * HD_ + cs;
            v0 = *(const float4*)src;
            v1 = *(const float4*)(src + 4);
        }
        const float scl = 0.125f;  // hd^-0.5
        qs[r][cs + 0] = v0.x * scl; qs[r][cs + 1] = v0.y * scl;
        qs[r][cs + 2] = v0.z * scl; qs[r][cs + 3] = v0.w * scl;
        qs[r][cs + 4] = v1.x * scl; qs[r][cs + 5] = v1.y * scl;
        qs[r][cs + 6] = v1.z * scl; qs[r][cs + 7] = v1.w * scl;
    }

    float m_r = -1e30f, l_r = 0.f;
    float acc[8];
#pragma unroll
    for (int q = 0; q < 8; ++q) acc[q] = 0.f;

    int ti  = tid & 31;   // phase-1 row
    int tj8 = tid >> 5;   // phase-1 col-group (0..7)

    for (int j0 = 0; j0 < N_; j0 += 64) {
        __syncthreads();
        // stage K/V tile
#pragma unroll
        for (int it = 0; it < 4; ++it) {
            int p = tid + it * 256;
            int jp = p >> 4;
            int cp = (p & 15) << 2;
            int j = j0 + jp;
            float4 kv = {0.f, 0.f, 0.f, 0.f}, vv = {0.f, 0.f, 0.f, 0.f};
            if (j < N_) {
                const float* base = qkv + (size_t)(b * N_ + j) * QKV_N + h * HD_ + cp;
                kv = *(const float4*)(base + 768);
                vv = *(const float4*)(base + 1536);
            }
            *(float4*)&ks[jp][cp] = kv;
            *(float4*)&vs[jp][cp] = vv;
        }
        __syncthreads();

        // phase 1: scores s = q.k + bias
        float s[8];
#pragma unroll
        for (int jj = 0; jj < 8; ++jj) s[jj] = 0.f;
#pragma unroll
        for (int kk = 0; kk < 64; kk += 4) {
            float4 qv = *(const float4*)&qs[ti][kk];
#pragma unroll
            for (int jj = 0; jj < 8; ++jj) {
                float4 kv = *(const float4*)&ks[tj8 * 8 + jj][kk];
                s[jj] += qv.x * kv.x + qv.y * kv.y + qv.z * kv.z + qv.w * kv.w;
            }
        }
        int ig = row0 + ti;
#pragma unroll
        for (int jj = 0; jj < 8; ++jj) {
            int jg = j0 + tj8 * 8 + jj;
            float val = -1e30f;
            if (ig < N_ && jg < N_) {
                int idx = rel_index[ig * N_ + jg];
                val = s[jj] + bias_table[idx * H_ + h];
            }
            sc[ti][tj8 * 8 + jj] = val;
        }
        __syncthreads();

        // phase 2: online softmax update (8 lanes per row)
        float pvv[8];
        float mx = -1e30f;
#pragma unroll
        for (int q = 0; q < 8; ++q) { pvv[q] = sc[r][cl + (q << 3)]; mx = fmaxf(mx, pvv[q]); }
        mx = fmaxf(mx, __shfl_xor(mx, 1));
        mx = fmaxf(mx, __shfl_xor(mx, 2));
        mx = fmaxf(mx, __shfl_xor(mx, 4));
        float m_new = fmaxf(m_r, mx);
        float corr = __expf(m_r - m_new);
        float sm = 0.f;
#pragma unroll
        for (int q = 0; q < 8; ++q) { pvv[q] = __expf(pvv[q] - m_new); sm += pvv[q]; }
        sm += __shfl_xor(sm, 1);
        sm += __shfl_xor(sm, 2);
        sm += __shfl_xor(sm, 4);
        l_r = l_r * corr + sm;
        m_r = m_new;
#pragma unroll
        for (int q = 0; q < 8; ++q) acc[q] *= corr;
#pragma unroll
        for (int q = 0; q < 8; ++q) sc[r][cl + (q << 3)] = pvv[q];
        __syncthreads();

        // phase 3: acc += P @ V
#pragma unroll 8
        for (int j = 0; j < 64; ++j) {
            float p = sc[r][j];
            float4 va = *(const float4*)&vs[j][cs];
            float4 vb = *(const float4*)&vs[j][cs + 4];
            acc[0] = fmaf(p, va.x, acc[0]); acc[1] = fmaf(p, va.y, acc[1]);
            acc[2] = fmaf(p, va.z, acc[2]); acc[3] = fmaf(p, va.w, acc[3]);
            acc[4] = fmaf(p, vb.x, acc[4]); acc[5] = fmaf(p, vb.y, acc[5]);
            acc[6] = fmaf(p, vb.z, acc[6]); acc[7] = fmaf(p, vb.w, acc[7]);
        }
    }

    int row = row0 + r;
    if (row < N_) {
        float inv = 1.0f / l_r;
        float4 o0 = {acc[0] * inv, acc[1] * inv, acc[2] * inv, acc[3] * inv};
        float4 o1 = {acc[4] * inv, acc[5] * inv, acc[6] * inv, acc[7] * inv};
        float* dst = attn_out + (size_t)(b * N_ + row) * C_ + h * HD_ + cs;
        *(float4*)dst = o0;
        *(float4*)(dst + 4) = o1;
    }
}

// ======================= cls row (head-mean of softmax row 0) =======================
__global__ __launch_bounds__(256) void cls_kernel(const float* __restrict__ qkv,
                                                  const float* __restrict__ bias_table,
                                                  const int* __restrict__ rel_index,
                                                  float* __restrict__ cls) {
    int b = blockIdx.x;
    __shared__ float q0[64];
    __shared__ float s[N_];
    __shared__ float accv[NIMG];
    __shared__ float red[256];
    int tid = threadIdx.x;
    for (int j = tid; j < NIMG; j += 256) accv[j] = 0.f;
    for (int h = 0; h < H_; ++h) {
        __syncthreads();
        if (tid < 64) q0[tid] = qkv[(size_t)(b * N_) * QKV_N + h * HD_ + tid] * 0.125f;
        __syncthreads();
        for (int j = tid; j < N_; j += 256) {
            const float* kr = qkv + (size_t)(b * N_ + j) * QKV_N + 768 + h * HD_;
            float d = 0.f;
            for (int kk = 0; kk < 64; ++kk) d += q0[kk] * kr[kk];
            s[j] = d + bias_table[rel_index[j] * H_ + h];
        }
        __syncthreads();
        float mx = -1e30f;
        for (int j = tid; j < N_; j += 256) mx = fmaxf(mx, s[j]);
        red[tid] = mx;
        __syncthreads();
        for (int st = 128; st > 0; st >>= 1) {
            if (tid < st) red[tid] = fmaxf(red[tid], red[tid + st]);
            __syncthreads();
        }
        float m = red[0];
        __syncthreads();
        float ssum = 0.f;
        for (int j = tid; j < N_; j += 256) ssum += expf(s[j] - m);
        red[tid] = ssum;
        __syncthreads();
        for (int st = 128; st > 0; st >>= 1) {
            if (tid < st) red[tid] += red[tid + st];
            __syncthreads();
        }
        float tot = red[0];
        __syncthreads();
        for (int j = tid; j < NIMG; j += 256) accv[j] += expf(s[j + 1] - m) / tot;
    }
    __syncthreads();
    for (int j = tid; j < NIMG; j += 256) cls[b * NIMG + j] = accv[j] * (1.0f / 12.0f);
}

// ======================= threefry2x32 (JAX) =======================
__device__ __forceinline__ void tf2x32(unsigned k0, unsigned k1, unsigned x0, unsigned x1,
                                       unsigned& o0, unsigned& o1) {
    unsigned ks2 = k0 ^ k1 ^ 0x1BD11BDAu;
    x0 += k0; x1 += k1;
#define ROTL_(v, d) (((v) << (d)) | ((v) >> (32 - (d))))
#define RND_(d) { x0 += x1; x1 = ROTL_(x1, d); x1 ^= x0; }
    RND_(13) RND_(15) RND_(26) RND_(6)
    x0 += k1; x1 += ks2 + 1u;
    RND_(17) RND_(29) RND_(16) RND_(24)
    x0 += ks2; x1 += k0 + 2u;
    RND_(13) RND_(15) RND_(26) RND_(6)
    x0 += k0; x1 += k1 + 3u;
    RND_(17) RND_(29) RND_(16) RND_(24)
    x0 += k1; x1 += ks2 + 4u;
    RND_(13) RND_(15) RND_(26) RND_(6)
    x0 += ks2; x1 += k0 + 5u;
    o0 = x0; o1 = x1;
#undef RND_
#undef ROTL_
}

// ======================= selection + img_idx =======================
__global__ __launch_bounds__(256) void select_kernel(const float* __restrict__ cls,
                                                     const float* __restrict__ token_w,
                                                     int* __restrict__ meta,
                                                     int* __restrict__ keep_idx,
                                                     int* __restrict__ img_idx) {
    __shared__ float red[256];
    __shared__ int ired[256];
    __shared__ int counts[16];
    __shared__ float c0[NIMG];
    __shared__ int keep_sh, nimg_sh;
    int tid = threadIdx.x;

    for (int b = 0; b < 16; ++b) {
        float sm = 0.f;
        for (int j = tid; j < NIMG; j += 256) sm += cls[b * NIMG + j];
        red[tid] = sm;
        __syncthreads();
        for (int st = 128; st > 0; st >>= 1) {
            if (tid < st) red[tid] += red[tid + st];
            __syncthreads();
        }
        float avg = red[0] * (1.0f / 576.0f);
        __syncthreads();
        int cnt = 0;
        for (int j = tid; j < NIMG; j += 256) cnt += (cls[b * NIMG + j] >= avg) ? 1 : 0;
        ired[tid] = cnt;
        __syncthreads();
        for (int st = 128; st > 0; st >>= 1) {
            if (tid < st) ired[tid] += ired[tid + st];
            __syncthreads();
        }
        if (tid == 0) counts[b] = ired[0];
        __syncthreads();
    }

    if (tid == 0) {
        int csum = 0, cmax = 0;
        for (int b2 = 0; b2 < 16; ++b2) {
            csum += counts[b2];
            if (counts[b2] > cmax) cmax = counts[b2];
        }
        double T = (double)csum / 16.0;
        double sig = 1.0 / (1.0 + exp(-(((double)cmax) - T) / 16.0));
        double kd = 576.0 * (0.6 + 0.4 * sig);
        int keep = (int)llrint(kd);            // banker's rounding == Python round
        int remaining = NIMG - keep;
        float w0 = token_w[0], w1 = token_w[1];
        float wm = fmaxf(w0, w1);
        float e0 = expf(w0 - wm), e1 = expf(w1 - wm);
        float wsm = e0 / (e0 + e1);
        int ntext = (int)((double)wsm * (double)remaining);   // int() truncation
        int nimg = remaining - ntext;
        meta[0] = keep; meta[1] = ntext; meta[2] = nimg;
        keep_sh = keep; nimg_sh = nimg;
    }
    __syncthreads();

    // top-k (stable rank) for batch 0
    for (int j = tid; j < NIMG; j += 256) c0[j] = cls[j];
    __syncthreads();
    int keep = keep_sh;
    for (int j = tid; j < NIMG; j += 256) {
        float v = c0[j];
        int rank = 0;
        for (int j2 = 0; j2 < NIMG; ++j2) {
            float v2 = c0[j2];
            rank += ((v2 > v) || (v2 == v && j2 < j)) ? 1 : 0;
        }
        if (rank < keep) keep_idx[rank] = j;
    }

    // img_idx via JAX threefry (partitionable / fold-like semantics)
    unsigned ki0, ki1, k1a, k1b, k2a, k2b;
    tf2x32(0u, 1u, 0u, 1u, ki0, ki1);       // ki = split(key(1))[1]
    tf2x32(ki0, ki1, 0u, 0u, k1a, k1b);     // k1 = split(ki)[0]
    tf2x32(ki0, ki1, 0u, 1u, k2a, k2b);     // k2 = split(ki)[1]
    int nimg = nimg_sh;
    int S = 16 * nimg;
    const unsigned span = 575u;
    const unsigned mult = ((65536u % span) * (65536u % span)) % span;  // 196
    for (int i = tid; i < S; i += 256) {
        unsigned h0, h1, l0, l1;
        tf2x32(k1a, k1b, 0u, (unsigned)i, h0, h1);
        tf2x32(k2a, k2b, 0u, (unsigned)i, l0, l1);
        unsigned hb = h0 ^ h1;
        unsigned lb = l0 ^ l1;
        unsigned off = ((hb % span) * mult + (lb % span)) % span;
        img_idx[i] = (int)off;
    }
}

// ======================= assemble output =======================
__global__ __launch_bounds__(192) void assemble_kernel(const float* __restrict__ xout,
                                                       const float* __restrict__ x,
                                                       const int* __restrict__ meta,
                                                       const int* __restrict__ keep_idx,
                                                       const int* __restrict__ img_idx,
                                                       float* __restrict__ out) {
    int gb = blockIdx.x;
    int token = gb % N_;
    int b = gb / N_;
    int keep = meta[0], ntext = meta[1], nimg = meta[2];
    const float* src;
    if (token == 0) {
        src = xout + (size_t)(b * N_) * C_;
    } else if (token <= keep) {
        src = xout + (size_t)(b * N_ + 1 + keep_idx[token - 1]) * C_;
    } else if (token <= keep + ntext) {
        src = x + (size_t)(b * N_ + 1) * C_;
    } else {
        int t = token - 1 - keep - ntext;
        src = x + (size_t)(b * N_ + 2 + img_idx[b * nimg + t]) * C_;
    }
    float4* d = (float4*)(out + (size_t)(b * N_ + token) * C_);
    d[threadIdx.x] = ((const float4*)src)[threadIdx.x];
}

// ======================= launch =======================
extern "C" void kernel_launch(void* const* d_in, const int* in_sizes, int n_in,
                              void* d_out, int out_size, void* d_ws, size_t ws_size,
                              hipStream_t stream) {
    const float* x          = (const float*)d_in[0];
    const float* qkv_w      = (const float*)d_in[1];
    const float* proj_w     = (const float*)d_in[2];
    const float* proj_b     = (const float*)d_in[3];
    const float* bias_table = (const float*)d_in[4];
    const float* token_w    = (const float*)d_in[5];
    const int*   rel_index  = (const int*)d_in[6];
    float* out = (float*)d_out;
    float* ws  = (float*)d_ws;

    float* qkv_buf  = ws + OFF_QKV;
    float* attn_out = ws + OFF_ATTNOUT;
    float* xout     = ws + OFF_XOUT;
    float* cls      = ws + OFF_CLS;
    int*   meta     = (int*)(ws + OFF_META);
    int*   keep_idx = meta + 8;
    int*   img_idx  = keep_idx + 576;

    // 1) qkv = x @ qkv_w^T   (M=9232, Nout=2304)
    sgemm_nt<<<dim3(QKV_N / 128, (M_ + 127) / 128), 256, 0, stream>>>(
        x, qkv_w, nullptr, qkv_buf, M_, QKV_N);
    // 2) cls_attn (softmax row 0, head-mean) — fp32, deterministic
    cls_kernel<<<dim3(B_), 256, 0, stream>>>(qkv_buf, bias_table, rel_index, cls);
    // 3) selection scalars + top-k + threefry img_idx
    select_kernel<<<dim3(1), 256, 0, stream>>>(cls, token_w, meta, keep_idx, img_idx);
    // 4) fused attention -> attn_out [b,n,h*64+d]
    attn_fused<<<dim3((N_ + 31) / 32, B_ * H_), 256, 0, stream>>>(
        qkv_buf, bias_table, rel_index, attn_out);
    // 5) xout = attn_out @ proj_w^T + proj_b
    sgemm_nt<<<dim3(C_ / 128, (M_ + 127) / 128), 256, 0, stream>>>(
        attn_out, proj_w, proj_b, xout, M_, C_);
    // 6) gather/concat final tokens
    assemble_kernel<<<dim3(B_ * N_), 192, 0, stream>>>(
        xout, x, meta, keep_idx, img_idx, out);
}

// Round 3
// 1012.937 us; speedup vs baseline: 2.4300x; 2.4300x over previous
//
#include <hip/hip_runtime.h>
#include <math.h>

#define B_    16
#define N_    577
#define C_    768
#define H_    12
#define HD_   64
#define M_    (B_ * N_)          // 9232
#define QKV_N 2304
#define NIMG  576

typedef _Float16 half8  __attribute__((ext_vector_type(8)));
typedef _Float16 half4v __attribute__((ext_vector_type(4)));
typedef float    floatx4 __attribute__((ext_vector_type(4)));

// ---- workspace layout (in floats) ----
#define OFF_QKV     0u
#define OFF_ATTNOUT 21270528u
#define OFF_XOUT    28360704u
#define OFF_CLS     35450880u
#define OFF_META    35460096u

// ======================= SGEMM: C = A @ B^T (+bias) =======================
__global__ __launch_bounds__(256) void sgemm_nt(const float* __restrict__ A,
                                                const float* __restrict__ Bw,
                                                const float* __restrict__ bias,
                                                float* __restrict__ Cout,
                                                int M, int Nout) {
    const int K = 768;
    __shared__ float As[8][128];
    __shared__ float Bs[8][128];
    int tid = threadIdx.x;
    int tx = tid & 15, ty = tid >> 4;
    int m0 = blockIdx.y * 128, n0 = blockIdx.x * 128;
    int ar = tid >> 1;
    int ac = (tid & 1) << 2;

    float c[8][8];
#pragma unroll
    for (int i = 0; i < 8; ++i)
#pragma unroll
        for (int j = 0; j < 8; ++j) c[i][j] = 0.f;

    const float* Aptr = A + (size_t)(m0 + ar) * K + ac;
    const float* Bptr = Bw + (size_t)(n0 + ar) * K + ac;
    bool aval = (m0 + ar) < M;
    bool bval = (n0 + ar) < Nout;

    for (int k0 = 0; k0 < K; k0 += 8) {
        float4 av = aval ? *(const float4*)(Aptr + k0) : float4{0.f, 0.f, 0.f, 0.f};
        float4 bv = bval ? *(const float4*)(Bptr + k0) : float4{0.f, 0.f, 0.f, 0.f};
        __syncthreads();
        As[ac + 0][ar] = av.x; As[ac + 1][ar] = av.y; As[ac + 2][ar] = av.z; As[ac + 3][ar] = av.w;
        Bs[ac + 0][ar] = bv.x; Bs[ac + 1][ar] = bv.y; Bs[ac + 2][ar] = bv.z; Bs[ac + 3][ar] = bv.w;
        __syncthreads();
#pragma unroll
        for (int kk = 0; kk < 8; ++kk) {
            float a[8], bb[8];
            *(float4*)&a[0]  = *(const float4*)&As[kk][ty * 8];
            *(float4*)&a[4]  = *(const float4*)&As[kk][ty * 8 + 4];
            *(float4*)&bb[0] = *(const float4*)&Bs[kk][tx * 8];
            *(float4*)&bb[4] = *(const float4*)&Bs[kk][tx * 8 + 4];
#pragma unroll
            for (int i = 0; i < 8; ++i)
#pragma unroll
                for (int j = 0; j < 8; ++j) c[i][j] = fmaf(a[i], bb[j], c[i][j]);
        }
    }

    int mbase = m0 + ty * 8;
    int nbase = n0 + tx * 8;
    float bvals[8];
#pragma unroll
    for (int j = 0; j < 8; ++j) bvals[j] = 0.f;
    if (bias) {
#pragma unroll
        for (int j = 0; j < 8; ++j) bvals[j] = bias[nbase + j];
    }
#pragma unroll
    for (int i = 0; i < 8; ++i) {
        int m = mbase + i;
        if (m < M) {
            float4 r0 = {c[i][0] + bvals[0], c[i][1] + bvals[1], c[i][2] + bvals[2], c[i][3] + bvals[3]};
            float4 r1 = {c[i][4] + bvals[4], c[i][5] + bvals[5], c[i][6] + bvals[6], c[i][7] + bvals[7]};
            float* dst = Cout + (size_t)m * Nout + nbase;
            *(float4*)dst = r0;
            *(float4*)(dst + 4) = r1;
        }
    }
}

// ======================= MFMA attention (split-f16, fp32-accurate) =======================
// Layouts (learn_hip m89-verified, 16x16x32 f16):
//   A-frag: lane holds A[row=lane&15][k=8*(lane>>4)+i], i=0..7 (half8)
//   B-frag: lane holds B[k=8*(lane>>4)+i][col=lane&15]
//   C/D:    lane,reg r -> D[row=4*(lane>>4)+r][col=lane&15]
// Per block: 4 waves x 32 rows = 128 rows; K/V tiles of 64 keys staged hi/lo in LDS.
// S = Qh*Kh + Qh*Kl + Ql*Kh (fp32-level accuracy); O += Pf16*(Vh+Vl).
__global__ __launch_bounds__(256, 2) void attn_mfma(const float* __restrict__ qkv,
                                                    const float* __restrict__ bias_table,
                                                    const int* __restrict__ rel_index,
                                                    float* __restrict__ attn_out) {
    __shared__ __attribute__((aligned(16))) _Float16 Kh[64][72];
    __shared__ __attribute__((aligned(16))) _Float16 Kl[64][72];
    __shared__ __attribute__((aligned(16))) _Float16 Vh[64][72];  // V^T: [d][key]
    __shared__ __attribute__((aligned(16))) _Float16 Vl[64][72];
    __shared__ __attribute__((aligned(16))) _Float16 Pb[4][32][72];

    int bh = blockIdx.y;
    int b = bh / H_, h = bh % H_;
    int tid = threadIdx.x;
    int wave = tid >> 6, lane = tid & 63;
    int g = lane >> 4, c = lane & 15;
    int row0 = blockIdx.x * 128 + wave * 32;

    // ---- load Q fragments (scaled, split hi/lo) ----
    half8 qh[2][2], ql[2][2];
#pragma unroll
    for (int rt = 0; rt < 2; ++rt) {
        int grow = row0 + rt * 16 + c;
#pragma unroll
        for (int kb = 0; kb < 2; ++kb) {
            floatx4 a0 = {0.f, 0.f, 0.f, 0.f}, a1 = {0.f, 0.f, 0.f, 0.f};
            if (grow < N_) {
                const float* src = qkv + (size_t)(b * N_ + grow) * QKV_N + h * HD_ + kb * 32 + g * 8;
                a0 = *(const floatx4*)src;
                a1 = *(const floatx4*)(src + 4);
            }
#pragma unroll
            for (int i = 0; i < 4; ++i) {
                float x0 = a0[i] * 0.125f;
                float x1 = a1[i] * 0.125f;
                _Float16 h0 = (_Float16)x0, h1 = (_Float16)x1;
                qh[rt][kb][i]     = h0; ql[rt][kb][i]     = (_Float16)(x0 - (float)h0);
                qh[rt][kb][i + 4] = h1; ql[rt][kb][i + 4] = (_Float16)(x1 - (float)h1);
            }
        }
    }

    floatx4 o[2][4];
    float mrun[2][4], lrun[2][4];
#pragma unroll
    for (int rt = 0; rt < 2; ++rt) {
#pragma unroll
        for (int t = 0; t < 4; ++t) { o[rt][t][0] = 0.f; o[rt][t][1] = 0.f; o[rt][t][2] = 0.f; o[rt][t][3] = 0.f; }
#pragma unroll
        for (int r = 0; r < 4; ++r) { mrun[rt][r] = -1e30f; lrun[rt][r] = 0.f; }
    }

    for (int j0 = 0; j0 < N_; j0 += 64) {
        __syncthreads();
        // ---- stage K/V tile (f32 -> hi/lo f16), V transposed ----
#pragma unroll
        for (int it = 0; it < 4; ++it) {
            int p = tid + it * 256;
            int kr = p >> 4;
            int c4 = (p & 15) << 2;
            int key = j0 + kr;
            floatx4 kv = {0.f, 0.f, 0.f, 0.f}, vv = {0.f, 0.f, 0.f, 0.f};
            if (key < N_) {
                const float* base = qkv + (size_t)(b * N_ + key) * QKV_N + h * HD_ + c4;
                kv = *(const floatx4*)(base + 768);
                vv = *(const floatx4*)(base + 1536);
            }
            half4v kh_, kl_;
#pragma unroll
            for (int i = 0; i < 4; ++i) {
                _Float16 hi = (_Float16)kv[i];
                kh_[i] = hi; kl_[i] = (_Float16)(kv[i] - (float)hi);
            }
            *(half4v*)&Kh[kr][c4] = kh_;
            *(half4v*)&Kl[kr][c4] = kl_;
#pragma unroll
            for (int i = 0; i < 4; ++i) {
                _Float16 hi = (_Float16)vv[i];
                Vh[c4 + i][kr] = hi;
                Vl[c4 + i][kr] = (_Float16)(vv[i] - (float)hi);
            }
        }
        __syncthreads();

        // ---- gather bias (+ OOB mask folded in as -1e30) ----
        float bv[2][4][4];
#pragma unroll
        for (int rt = 0; rt < 2; ++rt)
#pragma unroll
            for (int t = 0; t < 4; ++t)
#pragma unroll
                for (int r = 0; r < 4; ++r) {
                    int row = row0 + rt * 16 + 4 * g + r;
                    int key = j0 + t * 16 + c;
                    int rr = row < N_ ? row : N_ - 1;
                    int kk = key < N_ ? key : N_ - 1;
                    float bb = bias_table[rel_index[rr * N_ + kk] * H_ + h];
                    bv[rt][t][r] = (row < N_ && key < N_) ? bb : -1e30f;
                }

        // ---- S = Q K^T via 3 split MFMAs ----
        floatx4 s[2][4];
#pragma unroll
        for (int rt = 0; rt < 2; ++rt)
#pragma unroll
            for (int t = 0; t < 4; ++t) { s[rt][t][0] = 0.f; s[rt][t][1] = 0.f; s[rt][t][2] = 0.f; s[rt][t][3] = 0.f; }
#pragma unroll
        for (int t = 0; t < 4; ++t) {
#pragma unroll
            for (int kb = 0; kb < 2; ++kb) {
                half8 kh8 = *(const half8*)&Kh[t * 16 + c][kb * 32 + g * 8];
                half8 kl8 = *(const half8*)&Kl[t * 16 + c][kb * 32 + g * 8];
#pragma unroll
                for (int rt = 0; rt < 2; ++rt) {
                    s[rt][t] = __builtin_amdgcn_mfma_f32_16x16x32_f16(qh[rt][kb], kh8, s[rt][t], 0, 0, 0);
                    s[rt][t] = __builtin_amdgcn_mfma_f32_16x16x32_f16(qh[rt][kb], kl8, s[rt][t], 0, 0, 0);
                    s[rt][t] = __builtin_amdgcn_mfma_f32_16x16x32_f16(ql[rt][kb], kh8, s[rt][t], 0, 0, 0);
                }
            }
        }

        // ---- online softmax (rows live in D layout: row=4g+r, 64 cols across 16-lane group x 4 t) ----
#pragma unroll
        for (int rt = 0; rt < 2; ++rt) {
#pragma unroll
            for (int t = 0; t < 4; ++t)
#pragma unroll
                for (int r = 0; r < 4; ++r) s[rt][t][r] += bv[rt][t][r];
            float pm[4], mnew[4], corr[4], rs[4];
#pragma unroll
            for (int r = 0; r < 4; ++r) {
                pm[r] = fmaxf(fmaxf(s[rt][0][r], s[rt][1][r]), fmaxf(s[rt][2][r], s[rt][3][r]));
            }
#pragma unroll
            for (int r = 0; r < 4; ++r) {
                pm[r] = fmaxf(pm[r], __shfl_xor(pm[r], 1));
                pm[r] = fmaxf(pm[r], __shfl_xor(pm[r], 2));
                pm[r] = fmaxf(pm[r], __shfl_xor(pm[r], 4));
                pm[r] = fmaxf(pm[r], __shfl_xor(pm[r], 8));
                mnew[r] = fmaxf(mrun[rt][r], pm[r]);
                corr[r] = __expf(mrun[rt][r] - mnew[r]);
                rs[r] = 0.f;
            }
#pragma unroll
            for (int t = 0; t < 4; ++t)
#pragma unroll
                for (int r = 0; r < 4; ++r) {
                    float p = __expf(s[rt][t][r] - mnew[r]);
                    s[rt][t][r] = p;
                    rs[r] += p;
                }
#pragma unroll
            for (int r = 0; r < 4; ++r) {
                rs[r] += __shfl_xor(rs[r], 1);
                rs[r] += __shfl_xor(rs[r], 2);
                rs[r] += __shfl_xor(rs[r], 4);
                rs[r] += __shfl_xor(rs[r], 8);
                lrun[rt][r] = lrun[rt][r] * corr[r] + rs[r];
                mrun[rt][r] = mnew[r];
            }
#pragma unroll
            for (int t = 0; t < 4; ++t)
#pragma unroll
                for (int r = 0; r < 4; ++r) o[rt][t][r] *= corr[r];
            // store P (f16) to wave-private LDS for layout conversion (no barrier needed)
#pragma unroll
            for (int t = 0; t < 4; ++t)
#pragma unroll
                for (int r = 0; r < 4; ++r)
                    Pb[wave][rt * 16 + 4 * g + r][t * 16 + c] = (_Float16)s[rt][t][r];
        }

        // ---- O += P @ V (V split hi/lo) ----
#pragma unroll
        for (int kb = 0; kb < 2; ++kb) {
            half8 pa[2];
#pragma unroll
            for (int rt = 0; rt < 2; ++rt)
                pa[rt] = *(const half8*)&Pb[wave][rt * 16 + c][kb * 32 + g * 8];
#pragma unroll
            for (int t = 0; t < 4; ++t) {
                half8 vh8 = *(const half8*)&Vh[t * 16 + c][kb * 32 + g * 8];
                half8 vl8 = *(const half8*)&Vl[t * 16 + c][kb * 32 + g * 8];
#pragma unroll
                for (int rt = 0; rt < 2; ++rt) {
                    o[rt][t] = __builtin_amdgcn_mfma_f32_16x16x32_f16(pa[rt], vh8, o[rt][t], 0, 0, 0);
                    o[rt][t] = __builtin_amdgcn_mfma_f32_16x16x32_f16(pa[rt], vl8, o[rt][t], 0, 0, 0);
                }
            }
        }
    }

    // ---- epilogue: normalize and write ----
#pragma unroll
    for (int rt = 0; rt < 2; ++rt)
#pragma unroll
        for (int t = 0; t < 4; ++t)
#pragma unroll
            for (int r = 0; r < 4; ++r) {
                int row = row0 + rt * 16 + 4 * g + r;
                if (row < N_)
                    attn_out[(size_t)(b * N_ + row) * C_ + h * HD_ + t * 16 + c] = o[rt][t][r] / lrun[rt][r];
            }
}

// ======================= cls row (head-mean of softmax row 0) =======================
__global__ __launch_bounds__(256) void cls_kernel(const float* __restrict__ qkv,
                                                  const float* __restrict__ bias_table,
                                                  const int* __restrict__ rel_index,
                                                  float* __restrict__ cls) {
    int b = blockIdx.x;
    __shared__ float q0[64];
    __shared__ float s[N_];
    __shared__ float accv[NIMG];
    __shared__ float red[256];
    int tid = threadIdx.x;
    for (int j = tid; j < NIMG; j += 256) accv[j] = 0.f;
    for (int h = 0; h < H_; ++h) {
        __syncthreads();
        if (tid < 64) q0[tid] = qkv[(size_t)(b * N_) * QKV_N + h * HD_ + tid] * 0.125f;
        __syncthreads();
        for (int j = tid; j < N_; j += 256) {
            const float* kr = qkv + (size_t)(b * N_ + j) * QKV_N + 768 + h * HD_;
            float d = 0.f;
            for (int kk = 0; kk < 64; ++kk) d += q0[kk] * kr[kk];
            s[j] = d + bias_table[rel_index[j] * H_ + h];
        }
        __syncthreads();
        float mx = -1e30f;
        for (int j = tid; j < N_; j += 256) mx = fmaxf(mx, s[j]);
        red[tid] = mx;
        __syncthreads();
        for (int st = 128; st > 0; st >>= 1) {
            if (tid < st) red[tid] = fmaxf(red[tid], red[tid + st]);
            __syncthreads();
        }
        float m = red[0];
        __syncthreads();
        float ssum = 0.f;
        for (int j = tid; j < N_; j += 256) ssum += expf(s[j] - m);
        red[tid] = ssum;
        __syncthreads();
        for (int st = 128; st > 0; st >>= 1) {
            if (tid < st) red[tid] += red[tid + st];
            __syncthreads();
        }
        float tot = red[0];
        __syncthreads();
        for (int j = tid; j < NIMG; j += 256) accv[j] += expf(s[j + 1] - m) / tot;
    }
    __syncthreads();
    for (int j = tid; j < NIMG; j += 256) cls[b * NIMG + j] = accv[j] * (1.0f / 12.0f);
}

// ======================= threefry2x32 (JAX) =======================
__device__ __forceinline__ void tf2x32(unsigned k0, unsigned k1, unsigned x0, unsigned x1,
                                       unsigned& o0, unsigned& o1) {
    unsigned ks2 = k0 ^ k1 ^ 0x1BD11BDAu;
    x0 += k0; x1 += k1;
#define ROTL_(v, d) (((v) << (d)) | ((v) >> (32 - (d))))
#define RND_(d) { x0 += x1; x1 = ROTL_(x1, d); x1 ^= x0; }
    RND_(13) RND_(15) RND_(26) RND_(6)
    x0 += k1; x1 += ks2 + 1u;
    RND_(17) RND_(29) RND_(16) RND_(24)
    x0 += ks2; x1 += k0 + 2u;
    RND_(13) RND_(15) RND_(26) RND_(6)
    x0 += k0; x1 += k1 + 3u;
    RND_(17) RND_(29) RND_(16) RND_(24)
    x0 += k1; x1 += ks2 + 4u;
    RND_(13) RND_(15) RND_(26) RND_(6)
    x0 += ks2; x1 += k0 + 5u;
    o0 = x0; o1 = x1;
#undef RND_
#undef ROTL_
}

// ======================= selection + img_idx =======================
__global__ __launch_bounds__(256) void select_kernel(const float* __restrict__ cls,
                                                     const float* __restrict__ token_w,
                                                     int* __restrict__ meta,
                                                     int* __restrict__ keep_idx,
                                                     int* __restrict__ img_idx) {
    __shared__ float red[256];
    __shared__ int ired[256];
    __shared__ int counts[16];
    __shared__ float c0[NIMG];
    __shared__ int keep_sh, nimg_sh;
    int tid = threadIdx.x;

    for (int b = 0; b < 16; ++b) {
        float sm = 0.f;
        for (int j = tid; j < NIMG; j += 256) sm += cls[b * NIMG + j];
        red[tid] = sm;
        __syncthreads();
        for (int st = 128; st > 0; st >>= 1) {
            if (tid < st) red[tid] += red[tid + st];
            __syncthreads();
        }
        float avg = red[0] * (1.0f / 576.0f);
        __syncthreads();
        int cnt = 0;
        for (int j = tid; j < NIMG; j += 256) cnt += (cls[b * NIMG + j] >= avg) ? 1 : 0;
        ired[tid] = cnt;
        __syncthreads();
        for (int st = 128; st > 0; st >>= 1) {
            if (tid < st) ired[tid] += ired[tid + st];
            __syncthreads();
        }
        if (tid == 0) counts[b] = ired[0];
        __syncthreads();
    }

    if (tid == 0) {
        int csum = 0, cmax = 0;
        for (int b2 = 0; b2 < 16; ++b2) {
            csum += counts[b2];
            if (counts[b2] > cmax) cmax = counts[b2];
        }
        double T = (double)csum / 16.0;
        double sig = 1.0 / (1.0 + exp(-(((double)cmax) - T) / 16.0));
        double kd = 576.0 * (0.6 + 0.4 * sig);
        int keep = (int)llrint(kd);
        int remaining = NIMG - keep;
        float w0 = token_w[0], w1 = token_w[1];
        float wm = fmaxf(w0, w1);
        float e0 = expf(w0 - wm), e1 = expf(w1 - wm);
        float wsm = e0 / (e0 + e1);
        int ntext = (int)((double)wsm * (double)remaining);
        int nimg = remaining - ntext;
        meta[0] = keep; meta[1] = ntext; meta[2] = nimg;
        keep_sh = keep; nimg_sh = nimg;
    }
    __syncthreads();

    for (int j = tid; j < NIMG; j += 256) c0[j] = cls[j];
    __syncthreads();
    int keep = keep_sh;
    for (int j = tid; j < NIMG; j += 256) {
        float v = c0[j];
        int rank = 0;
        for (int j2 = 0; j2 < NIMG; ++j2) {
            float v2 = c0[j2];
            rank += ((v2 > v) || (v2 == v && j2 < j)) ? 1 : 0;
        }
        if (rank < keep) keep_idx[rank] = j;
    }

    unsigned ki0, ki1, k1a, k1b, k2a, k2b;
    tf2x32(0u, 1u, 0u, 1u, ki0, ki1);
    tf2x32(ki0, ki1, 0u, 0u, k1a, k1b);
    tf2x32(ki0, ki1, 0u, 1u, k2a, k2b);
    int nimg = nimg_sh;
    int S = 16 * nimg;
    const unsigned span = 575u;
    const unsigned mult = ((65536u % span) * (65536u % span)) % span;
    for (int i = tid; i < S; i += 256) {
        unsigned h0, h1, l0, l1;
        tf2x32(k1a, k1b, 0u, (unsigned)i, h0, h1);
        tf2x32(k2a, k2b, 0u, (unsigned)i, l0, l1);
        unsigned hb = h0 ^ h1;
        unsigned lb = l0 ^ l1;
        unsigned off = ((hb % span) * mult + (lb % span)) % span;
        img_idx[i] = (int)off;
    }
}

// ======================= assemble output =======================
__global__ __launch_bounds__(192) void assemble_kernel(const float* __restrict__ xout,
                                                       const float* __restrict__ x,
                                                       const int* __restrict__ meta,
                                                       const int* __restrict__ keep_idx,
                                                       const int* __restrict__ img_idx,
                                                       float* __restrict__ out) {
    int gb = blockIdx.x;
    int token = gb % N_;
    int b = gb / N_;
    int keep = meta[0], ntext = meta[1], nimg = meta[2];
    const float* src;
    if (token == 0) {
        src = xout + (size_t)(b * N_) * C_;
    } else if (token <= keep) {
        src = xout + (size_t)(b * N_ + 1 + keep_idx[token - 1]) * C_;
    } else if (token <= keep + ntext) {
        src = x + (size_t)(b * N_ + 1) * C_;
    } else {
        int t = token - 1 - keep - ntext;
        src = x + (size_t)(b * N_ + 2 + img_idx[b * nimg + t]) * C_;
    }
    float4* d = (float4*)(out + (size_t)(b * N_ + token) * C_);
    d[threadIdx.x] = ((const float4*)src)[threadIdx.x];
}

// ======================= launch =======================
extern "C" void kernel_launch(void* const* d_in, const int* in_sizes, int n_in,
                              void* d_out, int out_size, void* d_ws, size_t ws_size,
                              hipStream_t stream) {
    const float* x          = (const float*)d_in[0];
    const float* qkv_w      = (const float*)d_in[1];
    const float* proj_w     = (const float*)d_in[2];
    const float* proj_b     = (const float*)d_in[3];
    const float* bias_table = (const float*)d_in[4];
    const float* token_w    = (const float*)d_in[5];
    const int*   rel_index  = (const int*)d_in[6];
    float* out = (float*)d_out;
    float* ws  = (float*)d_ws;

    float* qkv_buf  = ws + OFF_QKV;
    float* attn_out = ws + OFF_ATTNOUT;
    float* xout     = ws + OFF_XOUT;
    float* cls      = ws + OFF_CLS;
    int*   meta     = (int*)(ws + OFF_META);
    int*   keep_idx = meta + 8;
    int*   img_idx  = keep_idx + 576;

    // 1) qkv = x @ qkv_w^T
    sgemm_nt<<<dim3(QKV_N / 128, (M_ + 127) / 128), 256, 0, stream>>>(
        x, qkv_w, nullptr, qkv_buf, M_, QKV_N);
    // 2) cls_attn (fp32, deterministic — selection path untouched)
    cls_kernel<<<dim3(B_), 256, 0, stream>>>(qkv_buf, bias_table, rel_index, cls);
    // 3) selection scalars + top-k + threefry img_idx
    select_kernel<<<dim3(1), 256, 0, stream>>>(cls, token_w, meta, keep_idx, img_idx);
    // 4) MFMA attention -> attn_out
    attn_mfma<<<dim3((N_ + 127) / 128, B_ * H_), 256, 0, stream>>>(
        qkv_buf, bias_table, rel_index, attn_out);
    // 5) xout = attn_out @ proj_w^T + proj_b
    sgemm_nt<<<dim3(C_ / 128, (M_ + 127) / 128), 256, 0, stream>>>(
        attn_out, proj_w, proj_b, xout, M_, C_);
    // 6) gather/concat final tokens
    assemble_kernel<<<dim3(B_ * N_), 192, 0, stream>>>(
        xout, x, meta, keep_idx, img_idx, out);
}

// Round 8
// 538.049 us; speedup vs baseline: 4.5747x; 1.8826x over previous
//
#include <hip/hip_runtime.h>
#include <math.h>

#define B_    16
#define N_    577
#define C_    768
#define H_    12
#define HD_   64
#define M_    (B_ * N_)          // 9232
#define QKV_N 2304
#define NIMG  576

typedef _Float16 half8  __attribute__((ext_vector_type(8)));
typedef _Float16 half4v __attribute__((ext_vector_type(4)));
typedef float    floatx4 __attribute__((ext_vector_type(4)));

// ---- workspace layout (f32 units) ----
#define OFF_QKV      0u           // 21,270,528 f32 (qkv fp32)
#define OFF_ATTNH    21270528u    // 3,545,088 f32 = 7,090,176 f16 (attn_out hi)
#define OFF_ATTNL    24815616u    // 3,545,088 f32 (attn_out lo)
#define OFF_XOUT     28360704u    // 7,090,176 f32 (xout; early: hosts xh/xl planes)
#define OFF_CLS      35450880u    // 9,216
#define OFF_CLSPART  35460096u    // 110,592 (16*12*576)
#define OFF_META     35570688u    // ints: meta[8], keep_idx[576], img_idx[9216]
#define OFF_WQKVH    35580544u    // 884,736 f32 = 1,769,472 f16
#define OFF_WQKVL    36465280u    // 884,736
#define OFF_WPROJH   37350016u    // 294,912 f32 = 589,824 f16
#define OFF_WPROJL   37644928u    // 294,912
#define OFF_BIASEXP  37939840u    // 1,998,174 f32 = 12*577*577 f16
// high-water ~39.94M f32 ~ 160 MB

// ======================= fp32 -> hi/lo f16 split =======================
__global__ __launch_bounds__(256) void split_kernel(const float* __restrict__ in,
                                                    _Float16* __restrict__ hi,
                                                    _Float16* __restrict__ lo, int n) {
    int i = (blockIdx.x * 256 + threadIdx.x) * 4;
    if (i >= n) return;
    float4 v = *(const float4*)(in + i);
    half4v h, l;
    float vv[4] = {v.x, v.y, v.z, v.w};
#pragma unroll
    for (int j = 0; j < 4; ++j) {
        _Float16 hj = (_Float16)vv[j];
        h[j] = hj;
        l[j] = (_Float16)(vv[j] - (float)hj);
    }
    *(half4v*)(hi + i) = h;
    *(half4v*)(lo + i) = l;
}

// ======================= bias_exp[h][i][j] = bias_table[rel_index[i][j]][h] =======================
__global__ __launch_bounds__(256) void bias_expand(const float* __restrict__ bias_table,
                                                   const int* __restrict__ rel_index,
                                                   _Float16* __restrict__ bias_exp) {
    int i = blockIdx.x, h = blockIdx.y;
    const int* ri = rel_index + (size_t)i * N_;
    _Float16* dst = bias_exp + ((size_t)h * N_ + i) * N_;
    for (int j = threadIdx.x; j < N_; j += 256)
        dst[j] = (_Float16)bias_table[ri[j] * H_ + h];
}

// ======================= split-f16 MFMA GEMM: C = A @ B^T (+bias) =======================
// A,B given as hi/lo f16 planes [M,768]/[Nout,768]. 128x128 tile, BK=32, 4 waves 2x2.
// 3-term accumulate: Ah*Bh + Ah*Bl + Al*Bh (fp32-level accuracy).
__global__ __launch_bounds__(256) void hgemm_nt_split(const _Float16* __restrict__ Ah,
                                                      const _Float16* __restrict__ Al,
                                                      const _Float16* __restrict__ Bh,
                                                      const _Float16* __restrict__ Bl,
                                                      const float* __restrict__ bias,
                                                      float* __restrict__ Cout,
                                                      int M, int Nout) {
    const int K = 768;
    __shared__ __attribute__((aligned(16))) _Float16 Ah_s[128][40];
    __shared__ __attribute__((aligned(16))) _Float16 Al_s[128][40];
    __shared__ __attribute__((aligned(16))) _Float16 Bh_s[128][40];
    __shared__ __attribute__((aligned(16))) _Float16 Bl_s[128][40];

    int tid = threadIdx.x;
    int wave = tid >> 6, lane = tid & 63;
    int g = lane >> 4, c = lane & 15;
    int wr = wave >> 1, wc = wave & 1;
    int m0 = blockIdx.y * 128, n0 = blockIdx.x * 128;

    floatx4 acc[4][4];
#pragma unroll
    for (int mi = 0; mi < 4; ++mi)
#pragma unroll
        for (int ni = 0; ni < 4; ++ni) { acc[mi][ni][0] = 0.f; acc[mi][ni][1] = 0.f; acc[mi][ni][2] = 0.f; acc[mi][ni][3] = 0.f; }

    int lr = tid >> 2;           // 0..63
    int lc = (tid & 3) << 3;     // 0,8,16,24

    for (int k0 = 0; k0 < K; k0 += 32) {
        __syncthreads();
#pragma unroll
        for (int hh = 0; hh < 2; ++hh) {
            int r2 = lr + hh * 64;
            size_t ga = (size_t)(m0 + r2) * K + k0 + lc;   // A rows may overrun M (reads stay in ws; stores guarded)
            size_t gb = (size_t)(n0 + r2) * K + k0 + lc;   // B tiles exact
            *(half8*)&Ah_s[r2][lc] = *(const half8*)(Ah + ga);
            *(half8*)&Al_s[r2][lc] = *(const half8*)(Al + ga);
            *(half8*)&Bh_s[r2][lc] = *(const half8*)(Bh + gb);
            *(half8*)&Bl_s[r2][lc] = *(const half8*)(Bl + gb);
        }
        __syncthreads();

        half8 af_h[4], af_l[4];
#pragma unroll
        for (int mi = 0; mi < 4; ++mi) {
            af_h[mi] = *(const half8*)&Ah_s[wr * 64 + mi * 16 + c][g * 8];
            af_l[mi] = *(const half8*)&Al_s[wr * 64 + mi * 16 + c][g * 8];
        }
#pragma unroll
        for (int ni = 0; ni < 4; ++ni) {
            half8 bf_h = *(const half8*)&Bh_s[wc * 64 + ni * 16 + c][g * 8];
            half8 bf_l = *(const half8*)&Bl_s[wc * 64 + ni * 16 + c][g * 8];
#pragma unroll
            for (int mi = 0; mi < 4; ++mi) {
                acc[mi][ni] = __builtin_amdgcn_mfma_f32_16x16x32_f16(af_h[mi], bf_h, acc[mi][ni], 0, 0, 0);
                acc[mi][ni] = __builtin_amdgcn_mfma_f32_16x16x32_f16(af_h[mi], bf_l, acc[mi][ni], 0, 0, 0);
                acc[mi][ni] = __builtin_amdgcn_mfma_f32_16x16x32_f16(af_l[mi], bf_h, acc[mi][ni], 0, 0, 0);
            }
        }
    }

#pragma unroll
    for (int ni = 0; ni < 4; ++ni) {
        int col = n0 + wc * 64 + ni * 16 + c;
        float bv = bias ? bias[col] : 0.f;
#pragma unroll
        for (int mi = 0; mi < 4; ++mi) {
#pragma unroll
            for (int r = 0; r < 4; ++r) {
                int row = m0 + wr * 64 + mi * 16 + 4 * g + r;
                if (row < M) Cout[(size_t)row * Nout + col] = acc[mi][ni][r] + bv;
            }
        }
    }
}

// ======================= MFMA attention (split-f16, fp32-accurate) =======================
__global__ __launch_bounds__(256, 2) void attn_mfma(const float* __restrict__ qkv,
                                                    const _Float16* __restrict__ bias_exp,
                                                    _Float16* __restrict__ attnh,
                                                    _Float16* __restrict__ attnl) {
    __shared__ __attribute__((aligned(16))) _Float16 Kh[64][72];
    __shared__ __attribute__((aligned(16))) _Float16 Kl[64][72];
    __shared__ __attribute__((aligned(16))) _Float16 Vh[64][72];  // V^T: [d][key]
    __shared__ __attribute__((aligned(16))) _Float16 Vl[64][72];
    __shared__ __attribute__((aligned(16))) _Float16 Pb[4][32][72];

    int bh = blockIdx.y;
    int b = bh / H_, h = bh % H_;
    int tid = threadIdx.x;
    int wave = tid >> 6, lane = tid & 63;
    int g = lane >> 4, c = lane & 15;
    int row0 = blockIdx.x * 128 + wave * 32;

    half8 qh[2][2], ql[2][2];
#pragma unroll
    for (int rt = 0; rt < 2; ++rt) {
        int grow = row0 + rt * 16 + c;
#pragma unroll
        for (int kb = 0; kb < 2; ++kb) {
            floatx4 a0 = {0.f, 0.f, 0.f, 0.f}, a1 = {0.f, 0.f, 0.f, 0.f};
            if (grow < N_) {
                const float* src = qkv + (size_t)(b * N_ + grow) * QKV_N + h * HD_ + kb * 32 + g * 8;
                a0 = *(const floatx4*)src;
                a1 = *(const floatx4*)(src + 4);
            }
#pragma unroll
            for (int i = 0; i < 4; ++i) {
                float x0 = a0[i] * 0.125f;
                float x1 = a1[i] * 0.125f;
                _Float16 h0 = (_Float16)x0, h1 = (_Float16)x1;
                qh[rt][kb][i]     = h0; ql[rt][kb][i]     = (_Float16)(x0 - (float)h0);
                qh[rt][kb][i + 4] = h1; ql[rt][kb][i + 4] = (_Float16)(x1 - (float)h1);
            }
        }
    }

    floatx4 o[2][4];
    float mrun[2][4], lrun[2][4];
#pragma unroll
    for (int rt = 0; rt < 2; ++rt) {
#pragma unroll
        for (int t = 0; t < 4; ++t) { o[rt][t][0] = 0.f; o[rt][t][1] = 0.f; o[rt][t][2] = 0.f; o[rt][t][3] = 0.f; }
#pragma unroll
        for (int r = 0; r < 4; ++r) { mrun[rt][r] = -1e30f; lrun[rt][r] = 0.f; }
    }

    for (int j0 = 0; j0 < N_; j0 += 64) {
        __syncthreads();
#pragma unroll
        for (int it = 0; it < 4; ++it) {
            int p = tid + it * 256;
            int kr = p >> 4;
            int c4 = (p & 15) << 2;
            int key = j0 + kr;
            floatx4 kv = {0.f, 0.f, 0.f, 0.f}, vv = {0.f, 0.f, 0.f, 0.f};
            if (key < N_) {
                const float* base = qkv + (size_t)(b * N_ + key) * QKV_N + h * HD_ + c4;
                kv = *(const floatx4*)(base + 768);
                vv = *(const floatx4*)(base + 1536);
            }
            half4v kh_, kl_;
#pragma unroll
            for (int i = 0; i < 4; ++i) {
                _Float16 hi = (_Float16)kv[i];
                kh_[i] = hi; kl_[i] = (_Float16)(kv[i] - (float)hi);
            }
            *(half4v*)&Kh[kr][c4] = kh_;
            *(half4v*)&Kl[kr][c4] = kl_;
#pragma unroll
            for (int i = 0; i < 4; ++i) {
                _Float16 hi = (_Float16)vv[i];
                Vh[c4 + i][kr] = hi;
                Vl[c4 + i][kr] = (_Float16)(vv[i] - (float)hi);
            }
        }
        __syncthreads();

        // bias from expanded table (coalesced 2B loads; OOB masked)
        float bv[2][4][4];
#pragma unroll
        for (int rt = 0; rt < 2; ++rt)
#pragma unroll
            for (int t = 0; t < 4; ++t)
#pragma unroll
                for (int r = 0; r < 4; ++r) {
                    int row = row0 + rt * 16 + 4 * g + r;
                    int key = j0 + t * 16 + c;
                    int rr = row < N_ ? row : N_ - 1;
                    int kk = key < N_ ? key : N_ - 1;
                    float bb = (float)bias_exp[((size_t)h * N_ + rr) * N_ + kk];
                    bv[rt][t][r] = (row < N_ && key < N_) ? bb : -1e30f;
                }

        floatx4 s[2][4];
#pragma unroll
        for (int rt = 0; rt < 2; ++rt)
#pragma unroll
            for (int t = 0; t < 4; ++t) { s[rt][t][0] = 0.f; s[rt][t][1] = 0.f; s[rt][t][2] = 0.f; s[rt][t][3] = 0.f; }
#pragma unroll
        for (int t = 0; t < 4; ++t) {
#pragma unroll
            for (int kb = 0; kb < 2; ++kb) {
                half8 kh8 = *(const half8*)&Kh[t * 16 + c][kb * 32 + g * 8];
                half8 kl8 = *(const half8*)&Kl[t * 16 + c][kb * 32 + g * 8];
#pragma unroll
                for (int rt = 0; rt < 2; ++rt) {
                    s[rt][t] = __builtin_amdgcn_mfma_f32_16x16x32_f16(qh[rt][kb], kh8, s[rt][t], 0, 0, 0);
                    s[rt][t] = __builtin_amdgcn_mfma_f32_16x16x32_f16(qh[rt][kb], kl8, s[rt][t], 0, 0, 0);
                    s[rt][t] = __builtin_amdgcn_mfma_f32_16x16x32_f16(ql[rt][kb], kh8, s[rt][t], 0, 0, 0);
                }
            }
        }

#pragma unroll
        for (int rt = 0; rt < 2; ++rt) {
#pragma unroll
            for (int t = 0; t < 4; ++t)
#pragma unroll
                for (int r = 0; r < 4; ++r) s[rt][t][r] += bv[rt][t][r];
            float pm[4], mnew[4], corr[4], rs[4];
#pragma unroll
            for (int r = 0; r < 4; ++r) {
                pm[r] = fmaxf(fmaxf(s[rt][0][r], s[rt][1][r]), fmaxf(s[rt][2][r], s[rt][3][r]));
            }
#pragma unroll
            for (int r = 0; r < 4; ++r) {
                pm[r] = fmaxf(pm[r], __shfl_xor(pm[r], 1));
                pm[r] = fmaxf(pm[r], __shfl_xor(pm[r], 2));
                pm[r] = fmaxf(pm[r], __shfl_xor(pm[r], 4));
                pm[r] = fmaxf(pm[r], __shfl_xor(pm[r], 8));
                mnew[r] = fmaxf(mrun[rt][r], pm[r]);
                corr[r] = __expf(mrun[rt][r] - mnew[r]);
                rs[r] = 0.f;
            }
#pragma unroll
            for (int t = 0; t < 4; ++t)
#pragma unroll
                for (int r = 0; r < 4; ++r) {
                    float p = __expf(s[rt][t][r] - mnew[r]);
                    s[rt][t][r] = p;
                    rs[r] += p;
                }
#pragma unroll
            for (int r = 0; r < 4; ++r) {
                rs[r] += __shfl_xor(rs[r], 1);
                rs[r] += __shfl_xor(rs[r], 2);
                rs[r] += __shfl_xor(rs[r], 4);
                rs[r] += __shfl_xor(rs[r], 8);
                lrun[rt][r] = lrun[rt][r] * corr[r] + rs[r];
                mrun[rt][r] = mnew[r];
            }
#pragma unroll
            for (int t = 0; t < 4; ++t)
#pragma unroll
                for (int r = 0; r < 4; ++r) o[rt][t][r] *= corr[r];
#pragma unroll
            for (int t = 0; t < 4; ++t)
#pragma unroll
                for (int r = 0; r < 4; ++r)
                    Pb[wave][rt * 16 + 4 * g + r][t * 16 + c] = (_Float16)s[rt][t][r];
        }

#pragma unroll
        for (int kb = 0; kb < 2; ++kb) {
            half8 pa[2];
#pragma unroll
            for (int rt = 0; rt < 2; ++rt)
                pa[rt] = *(const half8*)&Pb[wave][rt * 16 + c][kb * 32 + g * 8];
#pragma unroll
            for (int t = 0; t < 4; ++t) {
                half8 vh8 = *(const half8*)&Vh[t * 16 + c][kb * 32 + g * 8];
                half8 vl8 = *(const half8*)&Vl[t * 16 + c][kb * 32 + g * 8];
#pragma unroll
                for (int rt = 0; rt < 2; ++rt) {
                    o[rt][t] = __builtin_amdgcn_mfma_f32_16x16x32_f16(pa[rt], vh8, o[rt][t], 0, 0, 0);
                    o[rt][t] = __builtin_amdgcn_mfma_f32_16x16x32_f16(pa[rt], vl8, o[rt][t], 0, 0, 0);
                }
            }
        }
    }

    // epilogue: normalize and write hi/lo planes (feeds proj hgemm directly)
#pragma unroll
    for (int rt = 0; rt < 2; ++rt)
#pragma unroll
        for (int t = 0; t < 4; ++t)
#pragma unroll
            for (int r = 0; r < 4; ++r) {
                int row = row0 + rt * 16 + 4 * g + r;
                if (row < N_) {
                    float val = o[rt][t][r] / lrun[rt][r];
                    size_t idx = (size_t)(b * N_ + row) * C_ + h * HD_ + t * 16 + c;
                    _Float16 hi = (_Float16)val;
                    attnh[idx] = hi;
                    attnl[idx] = (_Float16)(val - (float)hi);
                }
            }
}

// ======================= cls: per-(b,h) softmax row 0 =======================
__global__ __launch_bounds__(256) void cls_head_kernel(const float* __restrict__ qkv,
                                                       const float* __restrict__ bias_table,
                                                       const int* __restrict__ rel_index,
                                                       float* __restrict__ cls_part) {
    int b = blockIdx.x, h = blockIdx.y;
    __shared__ float q0[64];
    __shared__ float s[N_];
    __shared__ float red[256];
    int tid = threadIdx.x;
    if (tid < 64) q0[tid] = qkv[(size_t)(b * N_) * QKV_N + h * HD_ + tid] * 0.125f;
    __syncthreads();
    for (int j = tid; j < N_; j += 256) {
        const float* kr = qkv + (size_t)(b * N_ + j) * QKV_N + 768 + h * HD_;
        float d = 0.f;
        for (int kk = 0; kk < 64; ++kk) d += q0[kk] * kr[kk];
        s[j] = d + bias_table[rel_index[j] * H_ + h];
    }
    __syncthreads();
    float mx = -1e30f;
    for (int j = tid; j < N_; j += 256) mx = fmaxf(mx, s[j]);
    red[tid] = mx;
    __syncthreads();
    for (int st = 128; st > 0; st >>= 1) {
        if (tid < st) red[tid] = fmaxf(red[tid], red[tid + st]);
        __syncthreads();
    }
    float m = red[0];
    __syncthreads();
    float ssum = 0.f;
    for (int j = tid; j < N_; j += 256) ssum += expf(s[j] - m);
    red[tid] = ssum;
    __syncthreads();
    for (int st = 128; st > 0; st >>= 1) {
        if (tid < st) red[tid] += red[tid + st];
        __syncthreads();
    }
    float tot = red[0];
    __syncthreads();
    float* dst = cls_part + (size_t)(b * H_ + h) * NIMG;
    for (int j = tid; j < NIMG; j += 256) dst[j] = expf(s[j + 1] - m) / tot;
}

__global__ __launch_bounds__(576) void cls_reduce_kernel(const float* __restrict__ cls_part,
                                                         float* __restrict__ cls) {
    int b = blockIdx.x;
    int j = threadIdx.x;
    float a = 0.f;
    for (int h = 0; h < H_; ++h) a += cls_part[(size_t)(b * H_ + h) * NIMG + j];
    cls[b * NIMG + j] = a * (1.0f / 12.0f);
}

// ======================= threefry2x32 (JAX) =======================
__device__ __forceinline__ void tf2x32(unsigned k0, unsigned k1, unsigned x0, unsigned x1,
                                       unsigned& o0, unsigned& o1) {
    unsigned ks2 = k0 ^ k1 ^ 0x1BD11BDAu;
    x0 += k0; x1 += k1;
#define ROTL_(v, d) (((v) << (d)) | ((v) >> (32 - (d))))
#define RND_(d) { x0 += x1; x1 = ROTL_(x1, d); x1 ^= x0; }
    RND_(13) RND_(15) RND_(26) RND_(6)
    x0 += k1; x1 += ks2 + 1u;
    RND_(17) RND_(29) RND_(16) RND_(24)
    x0 += ks2; x1 += k0 + 2u;
    RND_(13) RND_(15) RND_(26) RND_(6)
    x0 += k0; x1 += k1 + 3u;
    RND_(17) RND_(29) RND_(16) RND_(24)
    x0 += k1; x1 += ks2 + 4u;
    RND_(13) RND_(15) RND_(26) RND_(6)
    x0 += ks2; x1 += k0 + 5u;
    o0 = x0; o1 = x1;
#undef RND_
#undef ROTL_
}

// ======================= selection + img_idx =======================
__global__ __launch_bounds__(256) void select_kernel(const float* __restrict__ cls,
                                                     const float* __restrict__ token_w,
                                                     int* __restrict__ meta,
                                                     int* __restrict__ keep_idx,
                                                     int* __restrict__ img_idx) {
    __shared__ float red[256];
    __shared__ int ired[256];
    __shared__ int counts[16];
    __shared__ float c0[NIMG];
    __shared__ int keep_sh, nimg_sh;
    int tid = threadIdx.x;

    for (int b = 0; b < 16; ++b) {
        float sm = 0.f;
        for (int j = tid; j < NIMG; j += 256) sm += cls[b * NIMG + j];
        red[tid] = sm;
        __syncthreads();
        for (int st = 128; st > 0; st >>= 1) {
            if (tid < st) red[tid] += red[tid + st];
            __syncthreads();
        }
        float avg = red[0] * (1.0f / 576.0f);
        __syncthreads();
        int cnt = 0;
        for (int j = tid; j < NIMG; j += 256) cnt += (cls[b * NIMG + j] >= avg) ? 1 : 0;
        ired[tid] = cnt;
        __syncthreads();
        for (int st = 128; st > 0; st >>= 1) {
            if (tid < st) ired[tid] += ired[tid + st];
            __syncthreads();
        }
        if (tid == 0) counts[b] = ired[0];
        __syncthreads();
    }

    if (tid == 0) {
        int csum = 0, cmax = 0;
        for (int b2 = 0; b2 < 16; ++b2) {
            csum += counts[b2];
            if (counts[b2] > cmax) cmax = counts[b2];
        }
        double T = (double)csum / 16.0;
        double sig = 1.0 / (1.0 + exp(-(((double)cmax) - T) / 16.0));
        double kd = 576.0 * (0.6 + 0.4 * sig);
        int keep = (int)llrint(kd);
        int remaining = NIMG - keep;
        float w0 = token_w[0], w1 = token_w[1];
        float wm = fmaxf(w0, w1);
        float e0 = expf(w0 - wm), e1 = expf(w1 - wm);
        float wsm = e0 / (e0 + e1);
        int ntext = (int)((double)wsm * (double)remaining);
        int nimg = remaining - ntext;
        meta[0] = keep; meta[1] = ntext; meta[2] = nimg;
        keep_sh = keep; nimg_sh = nimg;
    }
    __syncthreads();

    for (int j = tid; j < NIMG; j += 256) c0[j] = cls[j];
    __syncthreads();
    int keep = keep_sh;
    for (int j = tid; j < NIMG; j += 256) {
        float v = c0[j];
        int rank = 0;
        for (int j2 = 0; j2 < NIMG; ++j2) {
            float v2 = c0[j2];
            rank += ((v2 > v) || (v2 == v && j2 < j)) ? 1 : 0;
        }
        if (rank < keep) keep_idx[rank] = j;
    }

    unsigned ki0, ki1, k1a, k1b, k2a, k2b;
    tf2x32(0u, 1u, 0u, 1u, ki0, ki1);
    tf2x32(ki0, ki1, 0u, 0u, k1a, k1b);
    tf2x32(ki0, ki1, 0u, 1u, k2a, k2b);
    int nimg = nimg_sh;
    int S = 16 * nimg;
    const unsigned span = 575u;
    const unsigned mult = ((65536u % span) * (65536u % span)) % span;
    for (int i = tid; i < S; i += 256) {
        unsigned h0, h1, l0, l1;
        tf2x32(k1a, k1b, 0u, (unsigned)i, h0, h1);
        tf2x32(k2a, k2b, 0u, (unsigned)i, l0, l1);
        unsigned hb = h0 ^ h1;
        unsigned lb = l0 ^ l1;
        unsigned off = ((hb % span) * mult + (lb % span)) % span;
        img_idx[i] = (int)off;
    }
}

// ======================= assemble output =======================
__global__ __launch_bounds__(192) void assemble_kernel(const float* __restrict__ xout,
                                                       const float* __restrict__ x,
                                                       const int* __restrict__ meta,
                                                       const int* __restrict__ keep_idx,
                                                       const int* __restrict__ img_idx,
                                                       float* __restrict__ out) {
    int gb = blockIdx.x;
    int token = gb % N_;
    int b = gb / N_;
    int keep = meta[0], ntext = meta[1], nimg = meta[2];
    const float* src;
    if (token == 0) {
        src = xout + (size_t)(b * N_) * C_;
    } else if (token <= keep) {
        src = xout + (size_t)(b * N_ + 1 + keep_idx[token - 1]) * C_;
    } else if (token <= keep + ntext) {
        src = x + (size_t)(b * N_ + 1) * C_;
    } else {
        int t = token - 1 - keep - ntext;
        src = x + (size_t)(b * N_ + 2 + img_idx[b * nimg + t]) * C_;
    }
    float4* d = (float4*)(out + (size_t)(b * N_ + token) * C_);
    d[threadIdx.x] = ((const float4*)src)[threadIdx.x];
}

// ======================= launch =======================
extern "C" void kernel_launch(void* const* d_in, const int* in_sizes, int n_in,
                              void* d_out, int out_size, void* d_ws, size_t ws_size,
                              hipStream_t stream) {
    const float* x          = (const float*)d_in[0];
    const float* qkv_w      = (const float*)d_in[1];
    const float* proj_w     = (const float*)d_in[2];
    const float* proj_b     = (const float*)d_in[3];
    const float* bias_table = (const float*)d_in[4];
    const float* token_w    = (const float*)d_in[5];
    const int*   rel_index  = (const int*)d_in[6];
    float* out = (float*)d_out;
    float* ws  = (float*)d_ws;

    float*     qkv_buf  = ws + OFF_QKV;
    _Float16*  attnh    = (_Float16*)(ws + OFF_ATTNH);
    _Float16*  attnl    = (_Float16*)(ws + OFF_ATTNL);
    float*     xout     = ws + OFF_XOUT;
    _Float16*  xh       = (_Float16*)(ws + OFF_XOUT);              // aliases xout (dead before GEMM3)
    _Float16*  xl       = (_Float16*)(ws + OFF_XOUT + 3545088u);
    float*     cls      = ws + OFF_CLS;
    float*     cls_part = ws + OFF_CLSPART;
    int*       meta     = (int*)(ws + OFF_META);
    int*       keep_idx = meta + 8;
    int*       img_idx  = keep_idx + 576;
    _Float16*  wqkvh    = (_Float16*)(ws + OFF_WQKVH);
    _Float16*  wqkvl    = (_Float16*)(ws + OFF_WQKVL);
    _Float16*  wprojh   = (_Float16*)(ws + OFF_WPROJH);
    _Float16*  wprojl   = (_Float16*)(ws + OFF_WPROJL);
    _Float16*  bias_exp = (_Float16*)(ws + OFF_BIASEXP);

    // 0) splits + bias expansion
    split_kernel<<<dim3(M_ * C_ / 1024), 256, 0, stream>>>(x, xh, xl, M_ * C_);
    split_kernel<<<dim3(QKV_N * C_ / 1024), 256, 0, stream>>>(qkv_w, wqkvh, wqkvl, QKV_N * C_);
    split_kernel<<<dim3(C_ * C_ / 1024), 256, 0, stream>>>(proj_w, wprojh, wprojl, C_ * C_);
    bias_expand<<<dim3(N_, H_), 256, 0, stream>>>(bias_table, rel_index, bias_exp);
    // 1) qkv = x @ qkv_w^T  (split-f16 MFMA)
    hgemm_nt_split<<<dim3(QKV_N / 128, (M_ + 127) / 128), 256, 0, stream>>>(
        xh, xl, wqkvh, wqkvl, nullptr, qkv_buf, M_, QKV_N);
    // 2) cls_attn (fp32, deterministic — selection path untouched)
    cls_head_kernel<<<dim3(B_, H_), 256, 0, stream>>>(qkv_buf, bias_table, rel_index, cls_part);
    cls_reduce_kernel<<<dim3(B_), 576, 0, stream>>>(cls_part, cls);
    // 3) selection scalars + top-k + threefry img_idx
    select_kernel<<<dim3(1), 256, 0, stream>>>(cls, token_w, meta, keep_idx, img_idx);
    // 4) MFMA attention -> attn hi/lo planes
    attn_mfma<<<dim3((N_ + 127) / 128, B_ * H_), 256, 0, stream>>>(
        qkv_buf, bias_exp, attnh, attnl);
    // 5) xout = attn_out @ proj_w^T + proj_b  (split-f16 MFMA)
    hgemm_nt_split<<<dim3(C_ / 128, (M_ + 127) / 128), 256, 0, stream>>>(
        attnh, attnl, wprojh, wprojl, proj_b, xout, M_, C_);
    // 6) gather/concat final tokens
    assemble_kernel<<<dim3(B_ * N_), 192, 0, stream>>>(
        xout, x, meta, keep_idx, img_idx, out);
}